// Round 4
// baseline (471.628 us; speedup 1.0000x reference)
//
#include <hip/hip_runtime.h>
#include <hip/hip_bf16.h>

typedef unsigned short u16;
typedef unsigned int   u32;
typedef __attribute__((ext_vector_type(8))) short s16x8;
typedef __attribute__((ext_vector_type(4))) float f32x4;

__device__ __forceinline__ u16 f2bf(float f) {
    u32 u = __float_as_uint(f);
    u += 0x7fff + ((u >> 16) & 1);   // RNE; inputs are finite
    return (u16)(u >> 16);
}

__device__ __forceinline__ f32x4 mfma16(s16x8 a, s16x8 b, f32x4 c) {
    return __builtin_amdgcn_mfma_f32_16x16x32_bf16(a, b, c, 0, 0, 0);
}

#define GLL16(g, l)                                                            \
    __builtin_amdgcn_global_load_lds(                                          \
        (const __attribute__((address_space(1))) void*)(g),                    \
        (__attribute__((address_space(3))) void*)(l), 16, 0, 0)

// ---------------- fp32 -> bf16 conversion (8 elems / thread) ----------------
__global__ void cvt_f32_bf16(const float* __restrict__ src, u16* __restrict__ dst, int n8) {
    int i = blockIdx.x * blockDim.x + threadIdx.x;
    if (i >= n8) return;
    const float4* s4 = reinterpret_cast<const float4*>(src);
    float4 a = s4[2 * i], b = s4[2 * i + 1];
    s16x8 o;
    o[0] = (short)f2bf(a.x); o[1] = (short)f2bf(a.y);
    o[2] = (short)f2bf(a.z); o[3] = (short)f2bf(a.w);
    o[4] = (short)f2bf(b.x); o[5] = (short)f2bf(b.y);
    o[6] = (short)f2bf(b.z); o[7] = (short)f2bf(b.w);
    reinterpret_cast<s16x8*>(dst)[i] = o;
}

// ---------------- C = A[M,K] @ B[N,K]^T, bf16 in, bf16/fp32 out -------------
// 128x128 tile, BK=32, 4 waves (2x2, 64x64 each), global_load_lds staging.
// LDS k-chunk XOR swizzle: slot(row,pos) holds global chunk pos^((row>>1)&3)
// -> fragment reads are 2-way (free) instead of 8-way conflicted.
template <int BF16_OUT>
__global__ __launch_bounds__(256, 2)
void gemm_bt(const u16* __restrict__ A, const u16* __restrict__ B,
             void* __restrict__ Cout, int M, int N, int K) {
    __shared__ __align__(16) u16 As[128 * 32];
    __shared__ __align__(16) u16 Bs[128 * 32];
    const int tid = threadIdx.x;
    const int w = tid >> 6, ln = tid & 63;
    const int m0 = blockIdx.y * 128, n0 = blockIdx.x * 128;
    const int wr = w >> 1, wc = w & 1;
    const int g = ln >> 4, c15 = ln & 15;
    f32x4 acc[4][4] = {};
    const int srow0 = w * 32 + (ln >> 2);
    const int spos = ln & 3;
    for (int k0 = 0; k0 < K; k0 += 32) {
        __syncthreads();
#pragma unroll
        for (int j = 0; j < 2; ++j) {
            int row = srow0 + j * 16;
            int ch = spos ^ ((row >> 1) & 3);
            const u16* ga = A + (size_t)(m0 + row) * K + k0 + ch * 8;
            GLL16(ga, (char*)As + (w * 32 + j * 16) * 64);
            const u16* gb = B + (size_t)(n0 + row) * K + k0 + ch * 8;
            GLL16(gb, (char*)Bs + (w * 32 + j * 16) * 64);
        }
        __syncthreads();
        s16x8 af[4], bfr[4];
#pragma unroll
        for (int ms = 0; ms < 4; ++ms) {
            int row = wr * 64 + ms * 16 + c15;
            int cp = g ^ ((row >> 1) & 3);
            af[ms] = *reinterpret_cast<const s16x8*>((const char*)As + row * 64 + cp * 16);
        }
#pragma unroll
        for (int ns = 0; ns < 4; ++ns) {
            int row = wc * 64 + ns * 16 + c15;
            int cp = g ^ ((row >> 1) & 3);
            bfr[ns] = *reinterpret_cast<const s16x8*>((const char*)Bs + row * 64 + cp * 16);
        }
#pragma unroll
        for (int ms = 0; ms < 4; ++ms)
#pragma unroll
            for (int ns = 0; ns < 4; ++ns)
                acc[ms][ns] = mfma16(af[ms], bfr[ns], acc[ms][ns]);
    }
#pragma unroll
    for (int ms = 0; ms < 4; ++ms)
#pragma unroll
        for (int ns = 0; ns < 4; ++ns)
#pragma unroll
            for (int r = 0; r < 4; ++r) {
                int row = m0 + wr * 64 + ms * 16 + g * 4 + r;
                int col = n0 + wc * 64 + ns * 16 + c15;
                float v = acc[ms][ns][r];
                if (BF16_OUT)
                    ((u16*)Cout)[(size_t)row * N + col] = f2bf(v);
                else
                    ((float*)Cout)[(size_t)row * N + col] = v;
            }
}

// ---------------- GQA causal flash attention --------------------------------
// qkv: [B*T][3072] bf16 (cols 0..2047 Q, 2048..2559 K, 2560..3071 V)
// out: [B*T][2048] bf16.  Block = (qtile of 128, head, batch), 4 waves.
__global__ __launch_bounds__(256, 2)
void attn_fwd(const u16* __restrict__ qkv, u16* __restrict__ outp) {
    const int T = 2048, RS = 3072;
    const int qb = blockIdx.x, h = blockIdx.y, b = blockIdx.z;
    const int kvh = h >> 2;
    const int tid = threadIdx.x, w = tid >> 6, ln = tid & 63;
    const int g = ln >> 4, c15 = ln & 15;
    __shared__ __align__(16) u16 Ks[64 * 64];      // swizzled rows of 128B
    __shared__ __align__(16) u16 Vt[64 * 72];      // V^T [d][kv], pad->72
    __shared__ __align__(16) u16 Ps[4][32 * 72];   // per-wave P
    const size_t base = (size_t)b * T * RS;
    const int qg0 = qb * 128 + w * 32;

    s16x8 qf[2][2];
#pragma unroll
    for (int ms = 0; ms < 2; ++ms)
#pragma unroll
        for (int ks = 0; ks < 2; ++ks)
            qf[ms][ks] = *reinterpret_cast<const s16x8*>(
                qkv + base + (size_t)(qg0 + ms * 16 + c15) * RS + h * 64 + ks * 32 + g * 8);

    f32x4 o[2][4] = {};
    float mrow[2][4], lrow[2][4];
#pragma unroll
    for (int ms = 0; ms < 2; ++ms)
#pragma unroll
        for (int r = 0; r < 4; ++r) { mrow[ms][r] = -INFINITY; lrow[ms][r] = 0.f; }

    const int ntiles = (qb + 1) * 2;
    for (int t = 0; t < ntiles; ++t) {
        __syncthreads();
        // stage K tile [64 kv][64 d], XOR-swizzled 16B chunks (pos^(row&7))
#pragma unroll
        for (int c = 0; c < 2; ++c) {
            int row = w * 16 + c * 8 + (ln >> 3);
            int pos = ln & 7;
            int ch = pos ^ (row & 7);
            const u16* gk = qkv + base + (size_t)(t * 64 + row) * RS + 2048 + kvh * 64 + ch * 8;
            GLL16(gk, (char*)Ks + (w * 16 + c * 8) * 128);
        }
        // stage V^T: dchunk-major mapping -> conflict-free LDS writes
#pragma unroll
        for (int j = 0; j < 2; ++j) {
            int cid = tid + j * 256;
            int dch = cid >> 6, tv = cid & 63;
            s16x8 vv = *reinterpret_cast<const s16x8*>(
                qkv + base + (size_t)(t * 64 + tv) * RS + 2560 + kvh * 64 + dch * 8);
#pragma unroll
            for (int i = 0; i < 8; ++i)
                Vt[(dch * 8 + i) * 72 + tv] = (u16)vv[i];
        }
        __syncthreads();

        // S = Q @ K^T
        f32x4 s[2][4] = {};
#pragma unroll
        for (int ks = 0; ks < 2; ++ks) {
            s16x8 kf[4];
#pragma unroll
            for (int ns = 0; ns < 4; ++ns) {
                int row = ns * 16 + c15;
                int ch = (ks * 4 + g) ^ (row & 7);
                kf[ns] = *reinterpret_cast<const s16x8*>((const char*)Ks + row * 128 + ch * 16);
            }
#pragma unroll
            for (int ms = 0; ms < 2; ++ms)
#pragma unroll
                for (int ns = 0; ns < 4; ++ns)
                    s[ms][ns] = mfma16(qf[ms][ks], kf[ns], s[ms][ns]);
        }

        // online softmax (rows live on 16-lane groups; reduce via shfl_xor)
#pragma unroll
        for (int ms = 0; ms < 2; ++ms) {
#pragma unroll
            for (int r = 0; r < 4; ++r) {
                int qrow = qg0 + ms * 16 + g * 4 + r;
                float mx = -INFINITY;
#pragma unroll
                for (int ns = 0; ns < 4; ++ns) {
                    int col = t * 64 + ns * 16 + c15;
                    float v = s[ms][ns][r] * 0.125f;
                    v = (col <= qrow) ? v : -INFINITY;
                    s[ms][ns][r] = v;
                    mx = fmaxf(mx, v);
                }
                mx = fmaxf(mx, __shfl_xor(mx, 1));
                mx = fmaxf(mx, __shfl_xor(mx, 2));
                mx = fmaxf(mx, __shfl_xor(mx, 4));
                mx = fmaxf(mx, __shfl_xor(mx, 8));
                float mold = mrow[ms][r];
                float mnew = fmaxf(mold, mx);        // finite after tile 0
                float fac = __expf(mold - mnew);     // expf(-inf)=0 at t=0
                float rsum = 0.f;
#pragma unroll
                for (int ns = 0; ns < 4; ++ns) {
                    float p = __expf(s[ms][ns][r] - mnew);
                    s[ms][ns][r] = p;
                    rsum += p;
                }
                rsum += __shfl_xor(rsum, 1);
                rsum += __shfl_xor(rsum, 2);
                rsum += __shfl_xor(rsum, 4);
                rsum += __shfl_xor(rsum, 8);
                mrow[ms][r] = mnew;
                lrow[ms][r] = lrow[ms][r] * fac + rsum;
#pragma unroll
                for (int ds = 0; ds < 4; ++ds) o[ms][ds][r] *= fac;
                // P to LDS (C-layout -> row-major) for the PV A-operand
#pragma unroll
                for (int ns = 0; ns < 4; ++ns)
                    Ps[w][(ms * 16 + g * 4 + r) * 72 + ns * 16 + c15] = f2bf(s[ms][ns][r]);
            }
        }
        __syncthreads();

        // O += P @ V
#pragma unroll
        for (int ks = 0; ks < 2; ++ks) {
            s16x8 pf[2], vf[4];
#pragma unroll
            for (int ms = 0; ms < 2; ++ms)
                pf[ms] = *reinterpret_cast<const s16x8*>(&Ps[w][(ms * 16 + c15) * 72 + ks * 32 + g * 8]);
#pragma unroll
            for (int ds = 0; ds < 4; ++ds)
                vf[ds] = *reinterpret_cast<const s16x8*>(&Vt[(ds * 16 + c15) * 72 + ks * 32 + g * 8]);
#pragma unroll
            for (int ms = 0; ms < 2; ++ms)
#pragma unroll
                for (int ds = 0; ds < 4; ++ds)
                    o[ms][ds] = mfma16(pf[ms], vf[ds], o[ms][ds]);
        }
    }

#pragma unroll
    for (int ms = 0; ms < 2; ++ms)
#pragma unroll
        for (int r = 0; r < 4; ++r) {
            float inv = 1.0f / lrow[ms][r];
            int qrow = qg0 + ms * 16 + g * 4 + r;
#pragma unroll
            for (int ds = 0; ds < 4; ++ds)
                outp[(size_t)(b * T + qrow) * 2048 + h * 64 + ds * 16 + c15] =
                    f2bf(o[ms][ds][r] * inv);
        }
}

// ---------------------------------------------------------------------------
extern "C" void kernel_launch(void* const* d_in, const int* in_sizes, int n_in,
                              void* d_out, int out_size, void* d_ws, size_t ws_size,
                              hipStream_t stream) {
    const float* x  = (const float*)d_in[0];
    const float* wq = (const float*)d_in[1];
    const float* wk = (const float*)d_in[2];
    const float* wv = (const float*)d_in[3];
    const float* wo = (const float*)d_in[4];

    u16* xb   = (u16*)d_ws;            // 8,388,608  : x bf16 [4096][2048]
    u16* wqkv = xb + 8388608;          // 6,291,456  : [3072][2048] (q|k|v rows)
    u16* wob  = wqkv + 6291456;        // 4,194,304  : [2048][2048]
    u16* qkvb = wob + 4194304;         // 12,582,912 : [4096][3072]
    u16* attb = qkvb + 12582912;       // 8,388,608  : [4096][2048]

    cvt_f32_bf16<<<4096, 256, 0, stream>>>(x, xb, 1048576);
    cvt_f32_bf16<<<2048, 256, 0, stream>>>(wq, wqkv, 524288);
    cvt_f32_bf16<<<512, 256, 0, stream>>>(wk, wqkv + 2048 * 2048, 131072);
    cvt_f32_bf16<<<512, 256, 0, stream>>>(wv, wqkv + 2560 * 2048, 131072);
    cvt_f32_bf16<<<2048, 256, 0, stream>>>(wo, wob, 524288);

    gemm_bt<1><<<dim3(24, 32), 256, 0, stream>>>(xb, wqkv, qkvb, 4096, 3072, 2048);
    attn_fwd<<<dim3(16, 32, 2), 256, 0, stream>>>(qkvb, attb);
    gemm_bt<0><<<dim3(16, 32), 256, 0, stream>>>(attb, wob, d_out, 4096, 2048, 2048);
}

// Round 5
// 376.834 us; speedup vs baseline: 1.2516x; 1.2516x over previous
//
#include <hip/hip_runtime.h>
#include <hip/hip_bf16.h>

typedef unsigned short u16;
typedef unsigned int   u32;
typedef __attribute__((ext_vector_type(8))) short s16x8;
typedef __attribute__((ext_vector_type(4))) float f32x4;

__device__ __forceinline__ u16 f2bf(float f) {
    u32 u = __float_as_uint(f);
    u += 0x7fff + ((u >> 16) & 1);   // RNE; inputs are finite
    return (u16)(u >> 16);
}

__device__ __forceinline__ f32x4 mfma16(s16x8 a, s16x8 b, f32x4 c) {
    return __builtin_amdgcn_mfma_f32_16x16x32_bf16(a, b, c, 0, 0, 0);
}

#define GLL16(g, l)                                                            \
    __builtin_amdgcn_global_load_lds(                                          \
        (const __attribute__((address_space(1))) void*)(g),                    \
        (__attribute__((address_space(3))) void*)(l), 16, 0, 0)

// ---------------- fp32 -> bf16 conversion (8 elems / thread) ----------------
__global__ void cvt_f32_bf16(const float* __restrict__ src, u16* __restrict__ dst, int n8) {
    int i = blockIdx.x * blockDim.x + threadIdx.x;
    if (i >= n8) return;
    const float4* s4 = reinterpret_cast<const float4*>(src);
    float4 a = s4[2 * i], b = s4[2 * i + 1];
    s16x8 o;
    o[0] = (short)f2bf(a.x); o[1] = (short)f2bf(a.y);
    o[2] = (short)f2bf(a.z); o[3] = (short)f2bf(a.w);
    o[4] = (short)f2bf(b.x); o[5] = (short)f2bf(b.y);
    o[6] = (short)f2bf(b.z); o[7] = (short)f2bf(b.w);
    reinterpret_cast<s16x8*>(dst)[i] = o;
}

// ---------------- C = A[M,K] @ B[N,K]^T, bf16 in, bf16/fp32 out -------------
// 128x128 tile, BK=32, 4 waves (2x2, 64x64 each), global_load_lds staging.
template <int BF16_OUT>
__global__ __launch_bounds__(256, 2)
void gemm_bt(const u16* __restrict__ A, const u16* __restrict__ B,
             void* __restrict__ Cout, int M, int N, int K) {
    __shared__ __align__(16) u16 As[128 * 32];
    __shared__ __align__(16) u16 Bs[128 * 32];
    const int tid = threadIdx.x;
    const int w = tid >> 6, ln = tid & 63;
    const int m0 = blockIdx.y * 128, n0 = blockIdx.x * 128;
    const int wr = w >> 1, wc = w & 1;
    const int g = ln >> 4, c15 = ln & 15;
    f32x4 acc[4][4] = {};
    const int srow0 = w * 32 + (ln >> 2);
    const int spos = ln & 3;
    for (int k0 = 0; k0 < K; k0 += 32) {
        __syncthreads();
#pragma unroll
        for (int j = 0; j < 2; ++j) {
            int row = srow0 + j * 16;
            int ch = spos ^ ((row >> 1) & 3);
            const u16* ga = A + (size_t)(m0 + row) * K + k0 + ch * 8;
            GLL16(ga, (char*)As + (w * 32 + j * 16) * 64);
            const u16* gb = B + (size_t)(n0 + row) * K + k0 + ch * 8;
            GLL16(gb, (char*)Bs + (w * 32 + j * 16) * 64);
        }
        __syncthreads();
        s16x8 af[4], bfr[4];
#pragma unroll
        for (int ms = 0; ms < 4; ++ms) {
            int row = wr * 64 + ms * 16 + c15;
            int cp = g ^ ((row >> 1) & 3);
            af[ms] = *reinterpret_cast<const s16x8*>((const char*)As + row * 64 + cp * 16);
        }
#pragma unroll
        for (int ns = 0; ns < 4; ++ns) {
            int row = wc * 64 + ns * 16 + c15;
            int cp = g ^ ((row >> 1) & 3);
            bfr[ns] = *reinterpret_cast<const s16x8*>((const char*)Bs + row * 64 + cp * 16);
        }
        __builtin_amdgcn_s_setprio(1);
#pragma unroll
        for (int ms = 0; ms < 4; ++ms)
#pragma unroll
            for (int ns = 0; ns < 4; ++ns)
                acc[ms][ns] = mfma16(af[ms], bfr[ns], acc[ms][ns]);
        __builtin_amdgcn_s_setprio(0);
    }
#pragma unroll
    for (int ms = 0; ms < 4; ++ms)
#pragma unroll
        for (int ns = 0; ns < 4; ++ns)
#pragma unroll
            for (int r = 0; r < 4; ++r) {
                int row = m0 + wr * 64 + ms * 16 + g * 4 + r;
                int col = n0 + wc * 64 + ns * 16 + c15;
                float v = acc[ms][ns][r];
                if (BF16_OUT)
                    ((u16*)Cout)[(size_t)row * N + col] = f2bf(v);
                else
                    ((float*)Cout)[(size_t)row * N + col] = v;
            }
}

// ---------------- GQA causal flash attention (balanced, KV-shared) ----------
// qkv: [B*T][3072] bf16 (cols 0..2047 Q, 2048..2559 K, 2560..3071 V)
// Block = (q-pair, kvh, b): 8 waves = 4 heads x 2 q-subtiles(32 rows).
// Processes q-tiles {pair, 31-pair} (64 rows each) -> uniform 33 kv-tiles.
// K/V of the GQA group staged ONCE per tile, shared by all 4 heads.
__global__ __launch_bounds__(512, 2)
void attn_fwd(const u16* __restrict__ qkv, u16* __restrict__ outp) {
    const int T = 2048, RS = 3072;
    const int pair = blockIdx.x, kvh = blockIdx.y, b = blockIdx.z;
    const int tid = threadIdx.x, w = tid >> 6, ln = tid & 63;
    const int g = ln >> 4, c15 = ln & 15;
    const int h = kvh * 4 + (w >> 1);        // head for this wave
    const int qs = w & 1;                    // q-subtile within 64-row q-tile
    __shared__ __align__(16) u16 Ks[64 * 64];     // [kv][d] swizzled 128B rows
    __shared__ __align__(16) u16 Vt[64 * 72];     // V^T [d][kv], pad->72
    __shared__ __align__(16) u16 Ps[8][32 * 72];  // per-wave P
    const size_t base = (size_t)b * T * RS;
    const float SCALE2 = 0.125f * 1.44269504088896f;  // scale * log2(e)

    for (int ph = 0; ph < 2; ++ph) {
        const int qb = ph ? (31 - pair) : pair;       // 64-row q-tile index
        const int qg0 = qb * 64 + qs * 32;            // wave's first q row

        s16x8 qf[2][2];
#pragma unroll
        for (int ms = 0; ms < 2; ++ms)
#pragma unroll
            for (int ks = 0; ks < 2; ++ks)
                qf[ms][ks] = *reinterpret_cast<const s16x8*>(
                    qkv + base + (size_t)(qg0 + ms * 16 + c15) * RS + h * 64 + ks * 32 + g * 8);

        f32x4 o[2][4] = {};
        float mrow[2][4], lrow[2][4];
#pragma unroll
        for (int ms = 0; ms < 2; ++ms)
#pragma unroll
            for (int r = 0; r < 4; ++r) { mrow[ms][r] = -INFINITY; lrow[ms][r] = 0.f; }

        const int nt = qb + 1;
        for (int t = 0; t < nt; ++t) {
            __syncthreads();
            // ---- stage K tile [64 kv][64 d]: 1 GLL16/thread, XOR swizzle --
            {
                int row = w * 8 + (ln >> 3);
                int ch = (ln & 7) ^ (row & 7);
                const u16* gk = qkv + base + (size_t)(t * 64 + row) * RS + 2048 + kvh * 64 + ch * 8;
                GLL16(gk, (char*)Ks + w * 1024);
            }
            // ---- stage V^T: wave w owns d-chunk w (8 d x 64 kv) ----------
            {
                s16x8 vv = *reinterpret_cast<const s16x8*>(
                    qkv + base + (size_t)(t * 64 + ln) * RS + 2560 + kvh * 64 + w * 8);
#pragma unroll
                for (int i = 0; i < 8; ++i)
                    Vt[(w * 8 + i) * 72 + ln] = (u16)vv[i];
            }
            __syncthreads();

            // ---- S = Q @ K^T ---------------------------------------------
            f32x4 s[2][4] = {};
#pragma unroll
            for (int ks = 0; ks < 2; ++ks) {
                s16x8 kf[4];
#pragma unroll
                for (int ns = 0; ns < 4; ++ns) {
                    int row = ns * 16 + c15;
                    int ch = (ks * 4 + g) ^ (row & 7);
                    kf[ns] = *reinterpret_cast<const s16x8*>((const char*)Ks + row * 128 + ch * 16);
                }
                __builtin_amdgcn_s_setprio(1);
#pragma unroll
                for (int ms = 0; ms < 2; ++ms)
#pragma unroll
                    for (int ns = 0; ns < 4; ++ns)
                        s[ms][ns] = mfma16(qf[ms][ks], kf[ns], s[ms][ns]);
                __builtin_amdgcn_s_setprio(0);
            }

            // ---- online softmax in exp2 domain ---------------------------
#pragma unroll
            for (int ms = 0; ms < 2; ++ms) {
#pragma unroll
                for (int r = 0; r < 4; ++r) {
                    int qrow = qg0 + ms * 16 + g * 4 + r;
                    float mx = -INFINITY;
#pragma unroll
                    for (int ns = 0; ns < 4; ++ns) {
                        int col = t * 64 + ns * 16 + c15;
                        float v = s[ms][ns][r] * SCALE2;
                        v = (col <= qrow) ? v : -INFINITY;
                        s[ms][ns][r] = v;
                        mx = fmaxf(mx, v);
                    }
                    mx = fmaxf(mx, __shfl_xor(mx, 1));
                    mx = fmaxf(mx, __shfl_xor(mx, 2));
                    mx = fmaxf(mx, __shfl_xor(mx, 4));
                    mx = fmaxf(mx, __shfl_xor(mx, 8));
                    float mold = mrow[ms][r];
                    float mnew = fmaxf(mold, mx);     // finite after tile 0
                    float fac = exp2f(mold - mnew);   // exp2(-inf)=0 at t=0
                    float rsum = 0.f;
#pragma unroll
                    for (int ns = 0; ns < 4; ++ns) {
                        float p = exp2f(s[ms][ns][r] - mnew);
                        s[ms][ns][r] = p;
                        rsum += p;
                    }
                    rsum += __shfl_xor(rsum, 1);
                    rsum += __shfl_xor(rsum, 2);
                    rsum += __shfl_xor(rsum, 4);
                    rsum += __shfl_xor(rsum, 8);
                    mrow[ms][r] = mnew;
                    lrow[ms][r] = lrow[ms][r] * fac + rsum;
#pragma unroll
                    for (int ds = 0; ds < 4; ++ds) o[ms][ds][r] *= fac;
#pragma unroll
                    for (int ns = 0; ns < 4; ++ns)
                        Ps[w][(ms * 16 + g * 4 + r) * 72 + ns * 16 + c15] = f2bf(s[ms][ns][r]);
                }
            }
            __syncthreads();   // Ps/Vt complete before PV reads; also gates restage

            // ---- O += P @ V ----------------------------------------------
#pragma unroll
            for (int ks = 0; ks < 2; ++ks) {
                s16x8 pf[2], vf[4];
#pragma unroll
                for (int ms = 0; ms < 2; ++ms)
                    pf[ms] = *reinterpret_cast<const s16x8*>(&Ps[w][(ms * 16 + c15) * 72 + ks * 32 + g * 8]);
#pragma unroll
                for (int ds = 0; ds < 4; ++ds)
                    vf[ds] = *reinterpret_cast<const s16x8*>(&Vt[(ds * 16 + c15) * 72 + ks * 32 + g * 8]);
                __builtin_amdgcn_s_setprio(1);
#pragma unroll
                for (int ms = 0; ms < 2; ++ms)
#pragma unroll
                    for (int ds = 0; ds < 4; ++ds)
                        o[ms][ds] = mfma16(pf[ms], vf[ds], o[ms][ds]);
                __builtin_amdgcn_s_setprio(0);
            }
        }

#pragma unroll
        for (int ms = 0; ms < 2; ++ms)
#pragma unroll
            for (int r = 0; r < 4; ++r) {
                float inv = 1.0f / lrow[ms][r];
                int qrow = qg0 + ms * 16 + g * 4 + r;
#pragma unroll
                for (int ds = 0; ds < 4; ++ds)
                    outp[(size_t)(b * T + qrow) * 2048 + h * 64 + ds * 16 + c15] =
                        f2bf(o[ms][ds][r] * inv);
            }
    }
}

// ---------------------------------------------------------------------------
extern "C" void kernel_launch(void* const* d_in, const int* in_sizes, int n_in,
                              void* d_out, int out_size, void* d_ws, size_t ws_size,
                              hipStream_t stream) {
    const float* x  = (const float*)d_in[0];
    const float* wq = (const float*)d_in[1];
    const float* wk = (const float*)d_in[2];
    const float* wv = (const float*)d_in[3];
    const float* wo = (const float*)d_in[4];

    u16* xb   = (u16*)d_ws;            // 8,388,608  : x bf16 [4096][2048]
    u16* wqkv = xb + 8388608;          // 6,291,456  : [3072][2048] (q|k|v rows)
    u16* wob  = wqkv + 6291456;        // 4,194,304  : [2048][2048]
    u16* qkvb = wob + 4194304;         // 12,582,912 : [4096][3072]
    u16* attb = qkvb + 12582912;       // 8,388,608  : [4096][2048]

    cvt_f32_bf16<<<4096, 256, 0, stream>>>(x, xb, 1048576);
    cvt_f32_bf16<<<2048, 256, 0, stream>>>(wq, wqkv, 524288);
    cvt_f32_bf16<<<512, 256, 0, stream>>>(wk, wqkv + 2048 * 2048, 131072);
    cvt_f32_bf16<<<512, 256, 0, stream>>>(wv, wqkv + 2560 * 2048, 131072);
    cvt_f32_bf16<<<2048, 256, 0, stream>>>(wo, wob, 524288);

    gemm_bt<1><<<dim3(24, 32), 256, 0, stream>>>(xb, wqkv, qkvb, 4096, 3072, 2048);
    attn_fwd<<<dim3(16, 8, 2), 512, 0, stream>>>(qkvb, attb);
    gemm_bt<0><<<dim3(16, 32), 256, 0, stream>>>(attb, wob, d_out, 4096, 2048, 2048);
}

// Round 6
// 331.083 us; speedup vs baseline: 1.4245x; 1.1382x over previous
//
#include <hip/hip_runtime.h>
#include <hip/hip_bf16.h>

typedef unsigned short u16;
typedef unsigned int   u32;
typedef __attribute__((ext_vector_type(8))) short s16x8;
typedef __attribute__((ext_vector_type(4))) float f32x4;

__device__ __forceinline__ u16 f2bf(float f) {
    u32 u = __float_as_uint(f);
    u += 0x7fff + ((u >> 16) & 1);   // RNE; inputs are finite
    return (u16)(u >> 16);
}

__device__ __forceinline__ u16 f2bf_fast(float f) {
    __hip_bfloat16 h = __float2bfloat16(f);
    return *reinterpret_cast<u16*>(&h);
}

__device__ __forceinline__ f32x4 mfma16(s16x8 a, s16x8 b, f32x4 c) {
    return __builtin_amdgcn_mfma_f32_16x16x32_bf16(a, b, c, 0, 0, 0);
}

#define GLL16(g, l)                                                            \
    __builtin_amdgcn_global_load_lds(                                          \
        (const __attribute__((address_space(1))) void*)(g),                    \
        (__attribute__((address_space(3))) void*)(l), 16, 0, 0)

// ---------------- fp32 -> bf16 conversion (8 elems / thread) ----------------
__global__ void cvt_f32_bf16(const float* __restrict__ src, u16* __restrict__ dst, int n8) {
    int i = blockIdx.x * blockDim.x + threadIdx.x;
    if (i >= n8) return;
    const float4* s4 = reinterpret_cast<const float4*>(src);
    float4 a = s4[2 * i], b = s4[2 * i + 1];
    s16x8 o;
    o[0] = (short)f2bf(a.x); o[1] = (short)f2bf(a.y);
    o[2] = (short)f2bf(a.z); o[3] = (short)f2bf(a.w);
    o[4] = (short)f2bf(b.x); o[5] = (short)f2bf(b.y);
    o[6] = (short)f2bf(b.z); o[7] = (short)f2bf(b.w);
    reinterpret_cast<s16x8*>(dst)[i] = o;
}

// all four weights in one launch: wq|wk|wv -> wqkv rows, wo -> wob
__global__ void cvt_weights(const float* __restrict__ wq, const float* __restrict__ wk,
                            const float* __restrict__ wv, const float* __restrict__ wo,
                            u16* __restrict__ wqkv, u16* __restrict__ wob) {
    int i = blockIdx.x * blockDim.x + threadIdx.x;   // 8-elem group id
    const float* src; u16* dst;
    if (i < 524288)       { src = wq + (size_t)i * 8;            dst = wqkv + (size_t)i * 8; }
    else if (i < 655360)  { int j = i - 524288; src = wk + (size_t)j * 8; dst = wqkv + 4194304 + (size_t)j * 8; }
    else if (i < 786432)  { int j = i - 655360; src = wv + (size_t)j * 8; dst = wqkv + 5242880 + (size_t)j * 8; }
    else                  { int j = i - 786432; src = wo + (size_t)j * 8; dst = wob + (size_t)j * 8; }
    const float4* s4 = reinterpret_cast<const float4*>(src);
    float4 a = s4[0], b = s4[1];
    s16x8 o;
    o[0] = (short)f2bf(a.x); o[1] = (short)f2bf(a.y);
    o[2] = (short)f2bf(a.z); o[3] = (short)f2bf(a.w);
    o[4] = (short)f2bf(b.x); o[5] = (short)f2bf(b.y);
    o[6] = (short)f2bf(b.z); o[7] = (short)f2bf(b.w);
    *reinterpret_cast<s16x8*>(dst) = o;
}

// ---------------- C = A[M,K] @ B[N,K]^T, bf16 in, bf16/fp32 out -------------
// 128x128 tile, BK=32, 4 waves (2x2, 64x64 each), global_load_lds staging.
template <int BF16_OUT>
__global__ __launch_bounds__(256, 2)
void gemm_bt(const u16* __restrict__ A, const u16* __restrict__ B,
             void* __restrict__ Cout, int M, int N, int K) {
    __shared__ __align__(16) u16 As[128 * 32];
    __shared__ __align__(16) u16 Bs[128 * 32];
    const int tid = threadIdx.x;
    const int w = tid >> 6, ln = tid & 63;
    const int m0 = blockIdx.y * 128, n0 = blockIdx.x * 128;
    const int wr = w >> 1, wc = w & 1;
    const int g = ln >> 4, c15 = ln & 15;
    f32x4 acc[4][4] = {};
    const int srow0 = w * 32 + (ln >> 2);
    const int spos = ln & 3;
    for (int k0 = 0; k0 < K; k0 += 32) {
        __syncthreads();
#pragma unroll
        for (int j = 0; j < 2; ++j) {
            int row = srow0 + j * 16;
            int ch = spos ^ ((row >> 1) & 3);
            const u16* ga = A + (size_t)(m0 + row) * K + k0 + ch * 8;
            GLL16(ga, (char*)As + (w * 32 + j * 16) * 64);
            const u16* gb = B + (size_t)(n0 + row) * K + k0 + ch * 8;
            GLL16(gb, (char*)Bs + (w * 32 + j * 16) * 64);
        }
        __syncthreads();
        s16x8 af[4], bfr[4];
#pragma unroll
        for (int ms = 0; ms < 4; ++ms) {
            int row = wr * 64 + ms * 16 + c15;
            int cp = g ^ ((row >> 1) & 3);
            af[ms] = *reinterpret_cast<const s16x8*>((const char*)As + row * 64 + cp * 16);
        }
#pragma unroll
        for (int ns = 0; ns < 4; ++ns) {
            int row = wc * 64 + ns * 16 + c15;
            int cp = g ^ ((row >> 1) & 3);
            bfr[ns] = *reinterpret_cast<const s16x8*>((const char*)Bs + row * 64 + cp * 16);
        }
        __builtin_amdgcn_s_setprio(1);
#pragma unroll
        for (int ms = 0; ms < 4; ++ms)
#pragma unroll
            for (int ns = 0; ns < 4; ++ns)
                acc[ms][ns] = mfma16(af[ms], bfr[ns], acc[ms][ns]);
        __builtin_amdgcn_s_setprio(0);
    }
#pragma unroll
    for (int ms = 0; ms < 4; ++ms)
#pragma unroll
        for (int ns = 0; ns < 4; ++ns)
#pragma unroll
            for (int r = 0; r < 4; ++r) {
                int row = m0 + wr * 64 + ms * 16 + g * 4 + r;
                int col = n0 + wc * 64 + ns * 16 + c15;
                float v = acc[ms][ns][r];
                if (BF16_OUT)
                    ((u16*)Cout)[(size_t)row * N + col] = f2bf(v);
                else
                    ((float*)Cout)[(size_t)row * N + col] = v;
            }
}

// ---------------- GQA causal flash attention --------------------------------
// Block = (pair, kvh, b), 4 waves (one head each, 32 q-rows), KVBLK=128.
// Processes q-tiles {pr, 63-pr} (32 rows each) -> uniform 17 kv-tiles/block.
// K/V staged once per tile, shared by the 4 heads of the GQA group.
// Mask applied only on the last tile; defer-rescale (THR=8, log2 domain);
// l kept as lane-local partials, reduced once in the epilogue.
__global__ __launch_bounds__(256, 2)
void attn_fwd(const u16* __restrict__ qkv, u16* __restrict__ outp) {
    const int T = 2048, RS = 3072;
    const int pr = blockIdx.x, kvh = blockIdx.y, b = blockIdx.z;
    const int tid = threadIdx.x, w = tid >> 6, ln = tid & 63;
    const int g = ln >> 4, c15 = ln & 15;
    const int h = kvh * 4 + w;                    // wave's head
    __shared__ __align__(16) u16 Ks[128 * 64];    // [kv][d] swizzled 128B rows
    __shared__ __align__(16) u16 Vt[64 * 136];    // V^T [d][kv], pad->136
    __shared__ __align__(16) u16 Ps[4][32 * 72];  // per-wave P (64-kv half)
    const size_t base = (size_t)b * T * RS;
    const float SCALE2 = 0.125f * 1.44269504088896f;  // scale * log2(e)
    const float THR = 8.0f;                            // defer-rescale (log2)

    for (int ph = 0; ph < 2; ++ph) {
        const int qt = ph ? (63 - pr) : pr;   // 32-row q-tile index
        const int qg0 = qt * 32;

        s16x8 qf[2][2];
#pragma unroll
        for (int ms = 0; ms < 2; ++ms)
#pragma unroll
            for (int ks = 0; ks < 2; ++ks)
                qf[ms][ks] = *reinterpret_cast<const s16x8*>(
                    qkv + base + (size_t)(qg0 + ms * 16 + c15) * RS + h * 64 + ks * 32 + g * 8);

        f32x4 o[2][4] = {};
        float mrow[2][4], lrow[2][4];
#pragma unroll
        for (int ms = 0; ms < 2; ++ms)
#pragma unroll
            for (int r = 0; r < 4; ++r) { mrow[ms][r] = -INFINITY; lrow[ms][r] = 0.f; }

        const int nt = (qt >> 2) + 1;         // 128-kv tiles
        for (int t = 0; t < nt; ++t) {
            __syncthreads();
            // ---- stage K [128 kv][64 d], XOR-swizzled 16B chunks ----------
#pragma unroll
            for (int j = 0; j < 4; ++j) {
                int row = w * 32 + j * 8 + (ln >> 3);
                int ch = (ln & 7) ^ (row & 7);
                const u16* gk = qkv + base + (size_t)(t * 128 + row) * RS + 2048 + kvh * 64 + ch * 8;
                GLL16(gk, (char*)Ks + (w * 32 + j * 8) * 128);
            }
            // ---- stage V^T [64 d][128 kv] ---------------------------------
#pragma unroll
            for (int j = 0; j < 4; ++j) {
                int cid = tid + j * 256;
                int kv = cid & 127, dch = cid >> 7;
                s16x8 vv = *reinterpret_cast<const s16x8*>(
                    qkv + base + (size_t)(t * 128 + kv) * RS + 2560 + kvh * 64 + dch * 8);
#pragma unroll
                for (int i = 0; i < 8; ++i)
                    Vt[(dch * 8 + i) * 136 + kv] = (u16)vv[i];
            }
            __syncthreads();

            // ---- S = Q @ K^T (s[2][8], kv 0..127) -------------------------
            f32x4 s[2][8] = {};
#pragma unroll
            for (int ks = 0; ks < 2; ++ks)
#pragma unroll
                for (int nh = 0; nh < 2; ++nh) {
                    s16x8 kf[4];
#pragma unroll
                    for (int n4 = 0; n4 < 4; ++n4) {
                        int row = (nh * 4 + n4) * 16 + c15;
                        int ch = (ks * 4 + g) ^ (row & 7);
                        kf[n4] = *reinterpret_cast<const s16x8*>((const char*)Ks + row * 128 + ch * 16);
                    }
                    __builtin_amdgcn_s_setprio(1);
#pragma unroll
                    for (int ms = 0; ms < 2; ++ms)
#pragma unroll
                        for (int n4 = 0; n4 < 4; ++n4)
                            s[ms][nh * 4 + n4] = mfma16(qf[ms][ks], kf[n4], s[ms][nh * 4 + n4]);
                    __builtin_amdgcn_s_setprio(0);
                }

            // ---- softmax: scale (+mask only on last tile), row max --------
            const bool lastT = (t == nt - 1);   // wave-uniform
            float mx2[2][4];
#pragma unroll
            for (int ms = 0; ms < 2; ++ms)
#pragma unroll
                for (int r = 0; r < 4; ++r) {
                    float mx = -INFINITY;
                    if (lastT) {
                        int qrow = qg0 + ms * 16 + g * 4 + r;
#pragma unroll
                        for (int ns = 0; ns < 8; ++ns) {
                            int col = t * 128 + ns * 16 + c15;
                            float v = s[ms][ns][r] * SCALE2;
                            v = (col <= qrow) ? v : -INFINITY;
                            s[ms][ns][r] = v;
                            mx = fmaxf(mx, v);
                        }
                    } else {
#pragma unroll
                        for (int ns = 0; ns < 8; ++ns) {
                            float v = s[ms][ns][r] * SCALE2;
                            s[ms][ns][r] = v;
                            mx = fmaxf(mx, v);
                        }
                    }
                    mx = fmaxf(mx, __shfl_xor(mx, 1));
                    mx = fmaxf(mx, __shfl_xor(mx, 2));
                    mx = fmaxf(mx, __shfl_xor(mx, 4));
                    mx = fmaxf(mx, __shfl_xor(mx, 8));
                    mx2[ms][r] = mx;
                }

            // ---- defer-rescale: only when max grew past THR ---------------
            float growth = -INFINITY;
#pragma unroll
            for (int ms = 0; ms < 2; ++ms)
#pragma unroll
                for (int r = 0; r < 4; ++r)
                    growth = fmaxf(growth, mx2[ms][r] - mrow[ms][r]);
            if (__any(growth > THR)) {
#pragma unroll
                for (int ms = 0; ms < 2; ++ms)
#pragma unroll
                    for (int r = 0; r < 4; ++r) {
                        float mnew = fmaxf(mrow[ms][r], mx2[ms][r]);
                        float fac = exp2f(mrow[ms][r] - mnew);   // 0 at t=0
                        mrow[ms][r] = mnew;
                        lrow[ms][r] *= fac;
#pragma unroll
                        for (int ds = 0; ds < 4; ++ds) o[ms][ds][r] *= fac;
                    }
            }

            // ---- P = exp2(S - m); lane-local l partials; store kv 0..63 ---
#pragma unroll
            for (int ms = 0; ms < 2; ++ms)
#pragma unroll
                for (int r = 0; r < 4; ++r) {
                    float m = mrow[ms][r];
                    float rs = 0.f;
#pragma unroll
                    for (int ns = 0; ns < 8; ++ns) {
                        float p = exp2f(s[ms][ns][r] - m);
                        s[ms][ns][r] = p;
                        rs += p;
                    }
                    lrow[ms][r] += rs;
                    int prow = ms * 16 + g * 4 + r;
#pragma unroll
                    for (int ns = 0; ns < 4; ++ns)
                        Ps[w][prow * 72 + ns * 16 + c15] = f2bf_fast(s[ms][ns][r]);
                }
            // ---- O += P @ V, kv 0..63 -------------------------------------
#pragma unroll
            for (int ks = 0; ks < 2; ++ks) {
                s16x8 pf[2], vf[4];
#pragma unroll
                for (int ms = 0; ms < 2; ++ms)
                    pf[ms] = *reinterpret_cast<const s16x8*>(&Ps[w][(ms * 16 + c15) * 72 + ks * 32 + g * 8]);
#pragma unroll
                for (int ds = 0; ds < 4; ++ds)
                    vf[ds] = *reinterpret_cast<const s16x8*>(&Vt[(ds * 16 + c15) * 136 + ks * 32 + g * 8]);
                __builtin_amdgcn_s_setprio(1);
#pragma unroll
                for (int ms = 0; ms < 2; ++ms)
#pragma unroll
                    for (int ds = 0; ds < 4; ++ds)
                        o[ms][ds] = mfma16(pf[ms], vf[ds], o[ms][ds]);
                __builtin_amdgcn_s_setprio(0);
            }
            // ---- store kv 64..127 then second PV pass ---------------------
#pragma unroll
            for (int ms = 0; ms < 2; ++ms)
#pragma unroll
                for (int r = 0; r < 4; ++r) {
                    int prow = ms * 16 + g * 4 + r;
#pragma unroll
                    for (int ns = 0; ns < 4; ++ns)
                        Ps[w][prow * 72 + ns * 16 + c15] = f2bf_fast(s[ms][ns + 4][r]);
                }
#pragma unroll
            for (int ks = 2; ks < 4; ++ks) {
                s16x8 pf[2], vf[4];
#pragma unroll
                for (int ms = 0; ms < 2; ++ms)
                    pf[ms] = *reinterpret_cast<const s16x8*>(&Ps[w][(ms * 16 + c15) * 72 + (ks - 2) * 32 + g * 8]);
#pragma unroll
                for (int ds = 0; ds < 4; ++ds)
                    vf[ds] = *reinterpret_cast<const s16x8*>(&Vt[(ds * 16 + c15) * 136 + ks * 32 + g * 8]);
                __builtin_amdgcn_s_setprio(1);
#pragma unroll
                for (int ms = 0; ms < 2; ++ms)
#pragma unroll
                    for (int ds = 0; ds < 4; ++ds)
                        o[ms][ds] = mfma16(pf[ms], vf[ds], o[ms][ds]);
                __builtin_amdgcn_s_setprio(0);
            }
        }

        // ---- epilogue: reduce l partials across the 16-lane row group -----
#pragma unroll
        for (int ms = 0; ms < 2; ++ms)
#pragma unroll
            for (int r = 0; r < 4; ++r) {
                float l = lrow[ms][r];
                l += __shfl_xor(l, 1);
                l += __shfl_xor(l, 2);
                l += __shfl_xor(l, 4);
                l += __shfl_xor(l, 8);
                float inv = 1.0f / l;
                int qrow = qg0 + ms * 16 + g * 4 + r;
#pragma unroll
                for (int ds = 0; ds < 4; ++ds)
                    outp[(size_t)(b * T + qrow) * 2048 + h * 64 + ds * 16 + c15] =
                        f2bf_fast(o[ms][ds][r] * inv);
            }
    }
}

// ---------------------------------------------------------------------------
extern "C" void kernel_launch(void* const* d_in, const int* in_sizes, int n_in,
                              void* d_out, int out_size, void* d_ws, size_t ws_size,
                              hipStream_t stream) {
    const float* x  = (const float*)d_in[0];
    const float* wq = (const float*)d_in[1];
    const float* wk = (const float*)d_in[2];
    const float* wv = (const float*)d_in[3];
    const float* wo = (const float*)d_in[4];

    u16* xb   = (u16*)d_ws;            // 8,388,608  : x bf16 [4096][2048]
    u16* wqkv = xb + 8388608;          // 6,291,456  : [3072][2048] (q|k|v rows)
    u16* wob  = wqkv + 6291456;        // 4,194,304  : [2048][2048]
    u16* qkvb = wob + 4194304;         // 12,582,912 : [4096][3072]
    u16* attb = qkvb + 12582912;       // 8,388,608  : [4096][2048]

    cvt_f32_bf16<<<4096, 256, 0, stream>>>(x, xb, 1048576);
    cvt_weights<<<5120, 256, 0, stream>>>(wq, wk, wv, wo, wqkv, wob);

    gemm_bt<1><<<dim3(24, 32), 256, 0, stream>>>(xb, wqkv, qkvb, 4096, 3072, 2048);
    attn_fwd<<<dim3(32, 8, 2), 256, 0, stream>>>(qkvb, attb);
    gemm_bt<0><<<dim3(16, 32), 256, 0, stream>>>(attb, wob, d_out, 4096, 2048, 2048);
}

// Round 8
// 314.871 us; speedup vs baseline: 1.4978x; 1.0515x over previous
//
#include <hip/hip_runtime.h>
#include <hip/hip_bf16.h>

typedef unsigned short u16;
typedef unsigned int   u32;
typedef __attribute__((ext_vector_type(8))) short s16x8;
typedef __attribute__((ext_vector_type(4))) float f32x4;

__device__ __forceinline__ u16 f2bf(float f) {
    u32 u = __float_as_uint(f);
    u += 0x7fff + ((u >> 16) & 1);   // RNE; inputs are finite
    return (u16)(u >> 16);
}

__device__ __forceinline__ u16 f2bf_fast(float f) {
    __hip_bfloat16 h = __float2bfloat16(f);
    return *reinterpret_cast<u16*>(&h);
}

__device__ __forceinline__ f32x4 mfma16(s16x8 a, s16x8 b, f32x4 c) {
    return __builtin_amdgcn_mfma_f32_16x16x32_bf16(a, b, c, 0, 0, 0);
}

#define GLL16(g, l)                                                            \
    __builtin_amdgcn_global_load_lds(                                          \
        (const __attribute__((address_space(1))) void*)(g),                    \
        (__attribute__((address_space(3))) void*)(l), 16, 0, 0)

// ---------------- fp32 -> bf16 conversion (8 elems / thread) ----------------
__global__ void cvt_f32_bf16(const float* __restrict__ src, u16* __restrict__ dst, int n8) {
    int i = blockIdx.x * blockDim.x + threadIdx.x;
    if (i >= n8) return;
    const float4* s4 = reinterpret_cast<const float4*>(src);
    float4 a = s4[2 * i], b = s4[2 * i + 1];
    s16x8 o;
    o[0] = (short)f2bf(a.x); o[1] = (short)f2bf(a.y);
    o[2] = (short)f2bf(a.z); o[3] = (short)f2bf(a.w);
    o[4] = (short)f2bf(b.x); o[5] = (short)f2bf(b.y);
    o[6] = (short)f2bf(b.z); o[7] = (short)f2bf(b.w);
    reinterpret_cast<s16x8*>(dst)[i] = o;
}

// all four weights in one launch: wq|wk|wv -> wqkv rows, wo -> wob
__global__ void cvt_weights(const float* __restrict__ wq, const float* __restrict__ wk,
                            const float* __restrict__ wv, const float* __restrict__ wo,
                            u16* __restrict__ wqkv, u16* __restrict__ wob) {
    int i = blockIdx.x * blockDim.x + threadIdx.x;   // 8-elem group id
    const float* src; u16* dst;
    if (i < 524288)       { src = wq + (size_t)i * 8;            dst = wqkv + (size_t)i * 8; }
    else if (i < 655360)  { int j = i - 524288; src = wk + (size_t)j * 8; dst = wqkv + 4194304 + (size_t)j * 8; }
    else if (i < 786432)  { int j = i - 655360; src = wv + (size_t)j * 8; dst = wqkv + 5242880 + (size_t)j * 8; }
    else                  { int j = i - 786432; src = wo + (size_t)j * 8; dst = wob + (size_t)j * 8; }
    const float4* s4 = reinterpret_cast<const float4*>(src);
    float4 a = s4[0], b = s4[1];
    s16x8 o;
    o[0] = (short)f2bf(a.x); o[1] = (short)f2bf(a.y);
    o[2] = (short)f2bf(a.z); o[3] = (short)f2bf(a.w);
    o[4] = (short)f2bf(b.x); o[5] = (short)f2bf(b.y);
    o[6] = (short)f2bf(b.z); o[7] = (short)f2bf(b.w);
    *reinterpret_cast<s16x8*>(dst) = o;
}

// ---------------- C = A[M,K] @ B[N,K]^T, bf16 in, bf16/fp32 out -------------
// 128x128 tile, BK=32, 4 waves (2x2, 64x64 each), global_load_lds staging.
// 1-D grid + bijective XCD swizzle (nwg % 8 == 0); launch_bounds(256,3)
// caps VGPR at 170 -> 3 blocks/CU co-resident (m97's overlap regime).
template <int BF16_OUT>
__global__ __launch_bounds__(256, 3)
void gemm_bt(const u16* __restrict__ A, const u16* __restrict__ B,
             void* __restrict__ Cout, int M, int N, int K, int nbx) {
    const int nwg = gridDim.x;
    const int cpx = nwg >> 3;                       // nwg % 8 == 0
    const int swz = (blockIdx.x & 7) * cpx + (blockIdx.x >> 3);
    const int by = swz / nbx, bx = swz - by * nbx;
    __shared__ __align__(16) u16 As[128 * 32];
    __shared__ __align__(16) u16 Bs[128 * 32];
    const int tid = threadIdx.x;
    const int w = tid >> 6, ln = tid & 63;
    const int m0 = by * 128, n0 = bx * 128;
    const int wr = w >> 1, wc = w & 1;
    const int g = ln >> 4, c15 = ln & 15;
    f32x4 acc[4][4] = {};
    const int srow0 = w * 32 + (ln >> 2);
    const int spos = ln & 3;
    for (int k0 = 0; k0 < K; k0 += 32) {
        __syncthreads();
#pragma unroll
        for (int j = 0; j < 2; ++j) {
            int row = srow0 + j * 16;
            int ch = spos ^ ((row >> 1) & 3);
            const u16* ga = A + (size_t)(m0 + row) * K + k0 + ch * 8;
            GLL16(ga, (char*)As + (w * 32 + j * 16) * 64);
            const u16* gb = B + (size_t)(n0 + row) * K + k0 + ch * 8;
            GLL16(gb, (char*)Bs + (w * 32 + j * 16) * 64);
        }
        __syncthreads();
        s16x8 af[4], bfr[4];
#pragma unroll
        for (int ms = 0; ms < 4; ++ms) {
            int row = wr * 64 + ms * 16 + c15;
            int cp = g ^ ((row >> 1) & 3);
            af[ms] = *reinterpret_cast<const s16x8*>((const char*)As + row * 64 + cp * 16);
        }
#pragma unroll
        for (int ns = 0; ns < 4; ++ns) {
            int row = wc * 64 + ns * 16 + c15;
            int cp = g ^ ((row >> 1) & 3);
            bfr[ns] = *reinterpret_cast<const s16x8*>((const char*)Bs + row * 64 + cp * 16);
        }
        __builtin_amdgcn_s_setprio(1);
#pragma unroll
        for (int ms = 0; ms < 4; ++ms)
#pragma unroll
            for (int ns = 0; ns < 4; ++ns)
                acc[ms][ns] = mfma16(af[ms], bfr[ns], acc[ms][ns]);
        __builtin_amdgcn_s_setprio(0);
    }
#pragma unroll
    for (int ms = 0; ms < 4; ++ms)
#pragma unroll
        for (int ns = 0; ns < 4; ++ns)
#pragma unroll
            for (int r = 0; r < 4; ++r) {
                int row = m0 + wr * 64 + ms * 16 + g * 4 + r;
                int col = n0 + wc * 64 + ns * 16 + c15;
                float v = acc[ms][ns][r];
                if (BF16_OUT)
                    ((u16*)Cout)[(size_t)row * N + col] = f2bf(v);
                else
                    ((float*)Cout)[(size_t)row * N + col] = v;
            }
}

// ---------------- GQA causal flash attention --------------------------------
// 512 blocks x 8 waves. Block = (pair of 32-row q-tiles, kvh, b); wave =
// (head in group, 16-row q-subtile). KVBLK=128 -> uniform 17 kv-tiles/block.
// K/V staged once per tile, shared by all 8 waves. Mask only on last tile;
// defer-rescale THR=8 (log2); lane-local l partials, reduced in epilogue.
// XCD swizzle: each XCD owns 2 whole (kvh,b) groups -> KV hot in its L2.
__global__ __launch_bounds__(512, 4)
void attn_fwd(const u16* __restrict__ qkv, u16* __restrict__ outp) {
    const int T = 2048, RS = 3072;
    const int swz = (blockIdx.x & 7) * 64 + (blockIdx.x >> 3);  // nwg=512
    const int pr = swz & 31, kvh = (swz >> 5) & 7, b = swz >> 8;
    const int tid = threadIdx.x, w = tid >> 6, ln = tid & 63;
    const int g = ln >> 4, c15 = ln & 15;
    const int h = kvh * 4 + (w >> 1);             // wave's head
    const int qs = w & 1;                         // 16-row q-subtile
    __shared__ __align__(16) u16 Ks[128 * 64];    // [kv][d] swizzled 128B rows
    __shared__ __align__(16) u16 Vt[64 * 136];    // V^T [d][kv], pad->136
    __shared__ __align__(16) u16 Ps[8][16 * 72];  // per-wave P (64-kv half)
    const size_t base = (size_t)b * T * RS;
    const float SCALE2 = 0.125f * 1.44269504088896f;  // scale * log2(e)
    const float THR = 8.0f;                            // defer-rescale (log2)

    for (int ph = 0; ph < 2; ++ph) {
        const int qb = ph ? (63 - pr) : pr;       // 32-row q-tile index
        const int qg0 = qb * 32 + qs * 16;        // wave's first q row

        s16x8 qf[2];
#pragma unroll
        for (int ks = 0; ks < 2; ++ks)
            qf[ks] = *reinterpret_cast<const s16x8*>(
                qkv + base + (size_t)(qg0 + c15) * RS + h * 64 + ks * 32 + g * 8);

        f32x4 o[4] = {};
        float mrow[4], lrow[4];
#pragma unroll
        for (int r = 0; r < 4; ++r) { mrow[r] = -INFINITY; lrow[r] = 0.f; }

        const int nt = (qb >> 2) + 1;             // 128-kv tiles
        for (int t = 0; t < nt; ++t) {
            __syncthreads();
            // ---- stage K [128 kv][64 d]: 2 GLL16/thread, XOR swizzle ------
#pragma unroll
            for (int j = 0; j < 2; ++j) {
                int row = j * 64 + w * 8 + (ln >> 3);
                int ch = (ln & 7) ^ (row & 7);
                const u16* gk = qkv + base + (size_t)(t * 128 + row) * RS + 2048 + kvh * 64 + ch * 8;
                GLL16(gk, (char*)Ks + (j * 64 + w * 8) * 128);
            }
            // ---- stage V^T [64 d][128 kv]: 2 rounds ------------------------
#pragma unroll
            for (int j = 0; j < 2; ++j) {
                int cid = tid + j * 512;
                int kv = cid & 127, dch = cid >> 7;
                s16x8 vv = *reinterpret_cast<const s16x8*>(
                    qkv + base + (size_t)(t * 128 + kv) * RS + 2560 + kvh * 64 + dch * 8);
#pragma unroll
                for (int i = 0; i < 8; ++i)
                    Vt[(dch * 8 + i) * 136 + kv] = (u16)vv[i];
            }
            __syncthreads();

            // ---- S = Q @ K^T (s[8], 16 q x 128 kv) -------------------------
            f32x4 s[8] = {};
#pragma unroll
            for (int ks = 0; ks < 2; ++ks)
#pragma unroll
                for (int nh = 0; nh < 2; ++nh) {
                    s16x8 kf[4];
#pragma unroll
                    for (int n4 = 0; n4 < 4; ++n4) {
                        int row = (nh * 4 + n4) * 16 + c15;
                        int ch = (ks * 4 + g) ^ (row & 7);
                        kf[n4] = *reinterpret_cast<const s16x8*>((const char*)Ks + row * 128 + ch * 16);
                    }
                    __builtin_amdgcn_s_setprio(1);
#pragma unroll
                    for (int n4 = 0; n4 < 4; ++n4)
                        s[nh * 4 + n4] = mfma16(qf[ks], kf[n4], s[nh * 4 + n4]);
                    __builtin_amdgcn_s_setprio(0);
                }

            // ---- softmax: scale (+mask only on last tile), row max ---------
            const bool lastT = (t == nt - 1);     // wave-uniform
            float mx2[4];
#pragma unroll
            for (int r = 0; r < 4; ++r) {
                float mx = -INFINITY;
                if (lastT) {
                    int qrow = qg0 + g * 4 + r;
#pragma unroll
                    for (int ns = 0; ns < 8; ++ns) {
                        int col = t * 128 + ns * 16 + c15;
                        float v = s[ns][r] * SCALE2;
                        v = (col <= qrow) ? v : -INFINITY;
                        s[ns][r] = v;
                        mx = fmaxf(mx, v);
                    }
                } else {
#pragma unroll
                    for (int ns = 0; ns < 8; ++ns) {
                        float v = s[ns][r] * SCALE2;
                        s[ns][r] = v;
                        mx = fmaxf(mx, v);
                    }
                }
                mx = fmaxf(mx, __shfl_xor(mx, 1));
                mx = fmaxf(mx, __shfl_xor(mx, 2));
                mx = fmaxf(mx, __shfl_xor(mx, 4));
                mx = fmaxf(mx, __shfl_xor(mx, 8));
                mx2[r] = mx;
            }

            // ---- defer-rescale: only when max grew past THR ----------------
            float growth = -INFINITY;
#pragma unroll
            for (int r = 0; r < 4; ++r) growth = fmaxf(growth, mx2[r] - mrow[r]);
            if (__any(growth > THR)) {
#pragma unroll
                for (int r = 0; r < 4; ++r) {
                    float mnew = fmaxf(mrow[r], mx2[r]);
                    float fac = exp2f(mrow[r] - mnew);   // 0 at t=0
                    mrow[r] = mnew;
                    lrow[r] *= fac;
#pragma unroll
                    for (int ds = 0; ds < 4; ++ds) o[ds][r] *= fac;
                }
            }

            // ---- P = exp2(S - m); lane-local l partials; store kv 0..63 ----
#pragma unroll
            for (int r = 0; r < 4; ++r) {
                float m = mrow[r];
                float rs = 0.f;
#pragma unroll
                for (int ns = 0; ns < 8; ++ns) {
                    float p = exp2f(s[ns][r] - m);
                    s[ns][r] = p;
                    rs += p;
                }
                lrow[r] += rs;
                int prow = g * 4 + r;
#pragma unroll
                for (int ns = 0; ns < 4; ++ns)
                    Ps[w][prow * 72 + ns * 16 + c15] = f2bf_fast(s[ns][r]);
            }
            // ---- O += P @ V, kv 0..63 --------------------------------------
#pragma unroll
            for (int ks = 0; ks < 2; ++ks) {
                s16x8 pf, vf[4];
                pf = *reinterpret_cast<const s16x8*>(&Ps[w][c15 * 72 + ks * 32 + g * 8]);
#pragma unroll
                for (int ds = 0; ds < 4; ++ds)
                    vf[ds] = *reinterpret_cast<const s16x8*>(&Vt[(ds * 16 + c15) * 136 + ks * 32 + g * 8]);
                __builtin_amdgcn_s_setprio(1);
#pragma unroll
                for (int ds = 0; ds < 4; ++ds)
                    o[ds] = mfma16(pf, vf[ds], o[ds]);
                __builtin_amdgcn_s_setprio(0);
            }
            // ---- store kv 64..127 then second PV pass ----------------------
#pragma unroll
            for (int r = 0; r < 4; ++r) {
                int prow = g * 4 + r;
#pragma unroll
                for (int ns = 0; ns < 4; ++ns)
                    Ps[w][prow * 72 + ns * 16 + c15] = f2bf_fast(s[ns + 4][r]);
            }
#pragma unroll
            for (int ks = 2; ks < 4; ++ks) {
                s16x8 pf, vf[4];
                pf = *reinterpret_cast<const s16x8*>(&Ps[w][c15 * 72 + (ks - 2) * 32 + g * 8]);
#pragma unroll
                for (int ds = 0; ds < 4; ++ds)
                    vf[ds] = *reinterpret_cast<const s16x8*>(&Vt[(ds * 16 + c15) * 136 + ks * 32 + g * 8]);
                __builtin_amdgcn_s_setprio(1);
#pragma unroll
                for (int ds = 0; ds < 4; ++ds)
                    o[ds] = mfma16(pf, vf[ds], o[ds]);
                __builtin_amdgcn_s_setprio(0);
            }
        }

        // ---- epilogue: reduce l partials across the 16-lane row group ------
#pragma unroll
        for (int r = 0; r < 4; ++r) {
            float l = lrow[r];
            l += __shfl_xor(l, 1);
            l += __shfl_xor(l, 2);
            l += __shfl_xor(l, 4);
            l += __shfl_xor(l, 8);
            float inv = 1.0f / l;
            int qrow = qg0 + g * 4 + r;
#pragma unroll
            for (int ds = 0; ds < 4; ++ds)
                outp[(size_t)(b * T + qrow) * 2048 + h * 64 + ds * 16 + c15] =
                    f2bf_fast(o[ds][r] * inv);
        }
    }
}

// ---------------------------------------------------------------------------
extern "C" void kernel_launch(void* const* d_in, const int* in_sizes, int n_in,
                              void* d_out, int out_size, void* d_ws, size_t ws_size,
                              hipStream_t stream) {
    const float* x  = (const float*)d_in[0];
    const float* wq = (const float*)d_in[1];
    const float* wk = (const float*)d_in[2];
    const float* wv = (const float*)d_in[3];
    const float* wo = (const float*)d_in[4];

    u16* xb   = (u16*)d_ws;            // 8,388,608  : x bf16 [4096][2048]
    u16* wqkv = xb + 8388608;          // 6,291,456  : [3072][2048] (q|k|v rows)
    u16* wob  = wqkv + 6291456;        // 4,194,304  : [2048][2048]
    u16* qkvb = wob + 4194304;         // 12,582,912 : [4096][3072]
    u16* attb = qkvb + 12582912;       // 8,388,608  : [4096][2048]

    cvt_f32_bf16<<<4096, 256, 0, stream>>>(x, xb, 1048576);
    cvt_weights<<<5120, 256, 0, stream>>>(wq, wk, wv, wo, wqkv, wob);

    gemm_bt<1><<<768, 256, 0, stream>>>(xb, wqkv, qkvb, 4096, 3072, 2048, 24);
    attn_fwd<<<512, 512, 0, stream>>>(qkvb, attb);
    gemm_bt<0><<<512, 256, 0, stream>>>(attb, wob, d_out, 4096, 2048, 2048, 16);
}

// Round 11
// 311.809 us; speedup vs baseline: 1.5126x; 1.0098x over previous
//
#include <hip/hip_runtime.h>
#include <hip/hip_bf16.h>

typedef unsigned short u16;
typedef unsigned int   u32;
typedef __attribute__((ext_vector_type(8))) short s16x8;
typedef __attribute__((ext_vector_type(4))) float f32x4;

__device__ __forceinline__ u16 f2bf(float f) {
    u32 u = __float_as_uint(f);
    u += 0x7fff + ((u >> 16) & 1);   // RNE; inputs are finite
    return (u16)(u >> 16);
}

__device__ __forceinline__ u16 f2bf_fast(float f) {
    __hip_bfloat16 h = __float2bfloat16(f);
    return *reinterpret_cast<u16*>(&h);
}

__device__ __forceinline__ f32x4 mfma16(s16x8 a, s16x8 b, f32x4 c) {
    return __builtin_amdgcn_mfma_f32_16x16x32_bf16(a, b, c, 0, 0, 0);
}

#define GLL16(g, l)                                                            \
    __builtin_amdgcn_global_load_lds(                                          \
        (const __attribute__((address_space(1))) void*)(g),                    \
        (__attribute__((address_space(3))) void*)(l), 16, 0, 0)

// ---------------- fp32 -> bf16 conversion (8 elems / thread) ----------------
__global__ void cvt_f32_bf16(const float* __restrict__ src, u16* __restrict__ dst, int n8) {
    int i = blockIdx.x * blockDim.x + threadIdx.x;
    if (i >= n8) return;
    const float4* s4 = reinterpret_cast<const float4*>(src);
    float4 a = s4[2 * i], b = s4[2 * i + 1];
    s16x8 o;
    o[0] = (short)f2bf(a.x); o[1] = (short)f2bf(a.y);
    o[2] = (short)f2bf(a.z); o[3] = (short)f2bf(a.w);
    o[4] = (short)f2bf(b.x); o[5] = (short)f2bf(b.y);
    o[6] = (short)f2bf(b.z); o[7] = (short)f2bf(b.w);
    reinterpret_cast<s16x8*>(dst)[i] = o;
}

// all four weights in one launch: wq|wk|wv -> wqkv rows, wo -> wob
__global__ void cvt_weights(const float* __restrict__ wq, const float* __restrict__ wk,
                            const float* __restrict__ wv, const float* __restrict__ wo,
                            u16* __restrict__ wqkv, u16* __restrict__ wob) {
    int i = blockIdx.x * blockDim.x + threadIdx.x;   // 8-elem group id
    const float* src; u16* dst;
    if (i < 524288)       { src = wq + (size_t)i * 8;            dst = wqkv + (size_t)i * 8; }
    else if (i < 655360)  { int j = i - 524288; src = wk + (size_t)j * 8; dst = wqkv + 4194304 + (size_t)j * 8; }
    else if (i < 786432)  { int j = i - 655360; src = wv + (size_t)j * 8; dst = wqkv + 5242880 + (size_t)j * 8; }
    else                  { int j = i - 786432; src = wo + (size_t)j * 8; dst = wob + (size_t)j * 8; }
    const float4* s4 = reinterpret_cast<const float4*>(src);
    float4 a = s4[0], b = s4[1];
    s16x8 o;
    o[0] = (short)f2bf(a.x); o[1] = (short)f2bf(a.y);
    o[2] = (short)f2bf(a.z); o[3] = (short)f2bf(a.w);
    o[4] = (short)f2bf(b.x); o[5] = (short)f2bf(b.y);
    o[6] = (short)f2bf(b.z); o[7] = (short)f2bf(b.w);
    *reinterpret_cast<s16x8*>(dst) = o;
}

// ---------------- C = A[M,K] @ B[N,K]^T, bf16 in, bf16/fp32 out -------------
// 128x128 tile, BK=32, 4 waves, DOUBLE-BUFFERED LDS + prefetch (T3 minimal
// 2-phase): STAGE(t+1) issued before compute(t); ONE barrier per K-step.
// QSCALE: QKV gemm pre-scales Q columns (n0<2048) by softmax scale*log2(e).
template <int BF16_OUT>
__global__ __launch_bounds__(256, 3)
void gemm_bt(const u16* __restrict__ A, const u16* __restrict__ B,
             void* __restrict__ Cout, int M, int N, int K, int nbx, int qcols) {
    const int nwg = gridDim.x;
    const int cpx = nwg >> 3;                       // nwg % 8 == 0
    const int swz = (blockIdx.x & 7) * cpx + (blockIdx.x >> 3);
    const int by = swz / nbx, bx = swz - by * nbx;
    __shared__ __align__(16) u16 As[2][128 * 32];
    __shared__ __align__(16) u16 Bs[2][128 * 32];
    const int tid = threadIdx.x;
    const int w = tid >> 6, ln = tid & 63;
    const int m0 = by * 128, n0 = bx * 128;
    const int wr = w >> 1, wc = w & 1;
    const int g = ln >> 4, c15 = ln & 15;
    f32x4 acc[4][4] = {};
    const int srow0 = w * 32 + (ln >> 2);
    const int spos = ln & 3;
    const int nk = K >> 5;

#define GSTAGE(buf, t)                                                          \
    {                                                                           \
        _Pragma("unroll")                                                       \
        for (int j = 0; j < 2; ++j) {                                           \
            int row = srow0 + j * 16;                                           \
            int ch = spos ^ ((row >> 1) & 3);                                   \
            const u16* ga = A + (size_t)(m0 + row) * K + (t) * 32 + ch * 8;     \
            GLL16(ga, (char*)As[buf] + (w * 32 + j * 16) * 64);                 \
            const u16* gb = B + (size_t)(n0 + row) * K + (t) * 32 + ch * 8;     \
            GLL16(gb, (char*)Bs[buf] + (w * 32 + j * 16) * 64);                 \
        }                                                                       \
    }

    GSTAGE(0, 0);
    __syncthreads();
    for (int t = 0; t < nk; ++t) {
        const int cur = t & 1;
        if (t + 1 < nk) GSTAGE(cur ^ 1, t + 1);
        s16x8 af[4], bfr[4];
#pragma unroll
        for (int ms = 0; ms < 4; ++ms) {
            int row = wr * 64 + ms * 16 + c15;
            int cp = g ^ ((row >> 1) & 3);
            af[ms] = *reinterpret_cast<const s16x8*>((const char*)As[cur] + row * 64 + cp * 16);
        }
#pragma unroll
        for (int ns = 0; ns < 4; ++ns) {
            int row = wc * 64 + ns * 16 + c15;
            int cp = g ^ ((row >> 1) & 3);
            bfr[ns] = *reinterpret_cast<const s16x8*>((const char*)Bs[cur] + row * 64 + cp * 16);
        }
        __builtin_amdgcn_s_setprio(1);
#pragma unroll
        for (int ms = 0; ms < 4; ++ms)
#pragma unroll
            for (int ns = 0; ns < 4; ++ns)
                acc[ms][ns] = mfma16(af[ms], bfr[ns], acc[ms][ns]);
        __builtin_amdgcn_s_setprio(0);
        __syncthreads();
    }
#undef GSTAGE

    const float qsc = (n0 < qcols) ? (0.125f * 1.44269504088896f) : 1.0f;
#pragma unroll
    for (int ms = 0; ms < 4; ++ms)
#pragma unroll
        for (int ns = 0; ns < 4; ++ns)
#pragma unroll
            for (int r = 0; r < 4; ++r) {
                int row = m0 + wr * 64 + ms * 16 + g * 4 + r;
                int col = n0 + wc * 64 + ns * 16 + c15;
                float v = acc[ms][ns][r];
                if (BF16_OUT)
                    ((u16*)Cout)[(size_t)row * N + col] = f2bf(v * qsc);
                else
                    ((float*)Cout)[(size_t)row * N + col] = v;
            }
}

// ---------------- GQA causal flash attention --------------------------------
// 512 blocks x 8 waves; wave = (head, 16-row q-subtile); KVBLK=128; paired
// q-tiles {pr,63-pr} -> uniform 17 tiles/block. 2-phase prefetch: K dbuf via
// global_load_lds, V reg-prefetch committed next iter (T14 split). Mid
// barrier = lgkmcnt-only (prefetch stays in flight); end barrier full drain.
// Q arrives PRE-SCALED by scale*log2(e) from the QKV GEMM.
__global__ __launch_bounds__(512, 4)
void attn_fwd(const u16* __restrict__ qkv, u16* __restrict__ outp) {
    const int T = 2048, RS = 3072;
    const int swz = (blockIdx.x & 7) * 64 + (blockIdx.x >> 3);  // nwg=512
    const int pr = swz & 31, kvh = (swz >> 5) & 7, b = swz >> 8;
    const int tid = threadIdx.x, w = tid >> 6, ln = tid & 63;
    const int g = ln >> 4, c15 = ln & 15;
    const int h = kvh * 4 + (w >> 1);             // wave's head
    const int qs = w & 1;                         // 16-row q-subtile
    __shared__ __align__(16) u16 Ks[2][128 * 64]; // dbuf, swizzled 128B rows
    __shared__ __align__(16) u16 Vt[64 * 136];    // V^T [d][kv], pad->136
    __shared__ __align__(16) u16 Ps[8][16 * 72];  // per-wave P (64-kv half)
    const size_t base = (size_t)b * T * RS;
    const float THR = 8.0f;                       // defer-rescale (log2)
    const int vkv0 = tid & 127, vdch0 = tid >> 7;          // V-load slot 0
    const int vkv1 = vkv0, vdch1 = vdch0 + 4;              // slot 1 (tid+512)

#define KSTAGE(buf, t)                                                          \
    {                                                                           \
        _Pragma("unroll")                                                       \
        for (int j = 0; j < 2; ++j) {                                           \
            int row = j * 64 + w * 8 + (ln >> 3);                               \
            int ch = (ln & 7) ^ (row & 7);                                      \
            const u16* gk = qkv + base + (size_t)((t) * 128 + row) * RS + 2048  \
                            + kvh * 64 + ch * 8;                                \
            GLL16(gk, (char*)Ks[buf] + (j * 64 + w * 8) * 128);                 \
        }                                                                       \
    }
#define VLOAD(t)                                                                \
    {                                                                           \
        vv0 = *reinterpret_cast<const s16x8*>(                                  \
            qkv + base + (size_t)((t) * 128 + vkv0) * RS + 2560                 \
            + kvh * 64 + vdch0 * 8);                                            \
        vv1 = *reinterpret_cast<const s16x8*>(                                  \
            qkv + base + (size_t)((t) * 128 + vkv1) * RS + 2560                 \
            + kvh * 64 + vdch1 * 8);                                            \
    }
#define VWRITE()                                                                \
    {                                                                           \
        _Pragma("unroll")                                                       \
        for (int i = 0; i < 8; ++i)                                             \
            Vt[(vdch0 * 8 + i) * 136 + vkv0] = (u16)vv0[i];                     \
        _Pragma("unroll")                                                       \
        for (int i = 0; i < 8; ++i)                                             \
            Vt[(vdch1 * 8 + i) * 136 + vkv1] = (u16)vv1[i];                     \
    }

    for (int ph = 0; ph < 2; ++ph) {
        const int qb = ph ? (63 - pr) : pr;       // 32-row q-tile index
        const int qg0 = qb * 32 + qs * 16;        // wave's first q row

        s16x8 qf[2];
#pragma unroll
        for (int ks = 0; ks < 2; ++ks)
            qf[ks] = *reinterpret_cast<const s16x8*>(
                qkv + base + (size_t)(qg0 + c15) * RS + h * 64 + ks * 32 + g * 8);

        f32x4 o[4] = {};
        float mrow[4], lrow[4];
#pragma unroll
        for (int r = 0; r < 4; ++r) { mrow[r] = -INFINITY; lrow[r] = 0.f; }

        const int nt = (qb >> 2) + 1;             // 128-kv tiles
        s16x8 vv0, vv1;
        KSTAGE(0, 0);
        VLOAD(0);
        __syncthreads();                          // tile 0 K landed

        for (int t = 0; t < nt; ++t) {
            const int cur = t & 1;
            // ---- commit tile t's V regs to LDS (overlaps with QK issue) ---
            VWRITE();
            // ---- prefetch tile t+1 (flies under QK+softmax+PV) ------------
            s16x8 nv0, nv1;
            if (t + 1 < nt) {
                KSTAGE(cur ^ 1, t + 1);
                nv0 = *reinterpret_cast<const s16x8*>(
                    qkv + base + (size_t)((t + 1) * 128 + vkv0) * RS + 2560 + kvh * 64 + vdch0 * 8);
                nv1 = *reinterpret_cast<const s16x8*>(
                    qkv + base + (size_t)((t + 1) * 128 + vkv1) * RS + 2560 + kvh * 64 + vdch1 * 8);
            }

            // ---- S = Q @ K^T (s[8], 16 q x 128 kv) ------------------------
            f32x4 s[8] = {};
#pragma unroll
            for (int ks = 0; ks < 2; ++ks)
#pragma unroll
                for (int nh = 0; nh < 2; ++nh) {
                    s16x8 kf[4];
#pragma unroll
                    for (int n4 = 0; n4 < 4; ++n4) {
                        int row = (nh * 4 + n4) * 16 + c15;
                        int ch = (ks * 4 + g) ^ (row & 7);
                        kf[n4] = *reinterpret_cast<const s16x8*>(
                            (const char*)Ks[cur] + row * 128 + ch * 16);
                    }
                    __builtin_amdgcn_s_setprio(1);
#pragma unroll
                    for (int n4 = 0; n4 < 4; ++n4)
                        s[nh * 4 + n4] = mfma16(qf[ks], kf[n4], s[nh * 4 + n4]);
                    __builtin_amdgcn_s_setprio(0);
                }

            // ---- softmax: row max (mask only on last tile; Q pre-scaled) --
            const bool lastT = (t == nt - 1);     // wave-uniform
            float mx2[4];
#pragma unroll
            for (int r = 0; r < 4; ++r) {
                float mx = -INFINITY;
                if (lastT) {
                    int qrow = qg0 + g * 4 + r;
#pragma unroll
                    for (int ns = 0; ns < 8; ++ns) {
                        int col = t * 128 + ns * 16 + c15;
                        float v = s[ns][r];
                        v = (col <= qrow) ? v : -INFINITY;
                        s[ns][r] = v;
                        mx = fmaxf(mx, v);
                    }
                } else {
#pragma unroll
                    for (int ns = 0; ns < 8; ++ns) mx = fmaxf(mx, s[ns][r]);
                }
                mx = fmaxf(mx, __shfl_xor(mx, 1));
                mx = fmaxf(mx, __shfl_xor(mx, 2));
                mx = fmaxf(mx, __shfl_xor(mx, 4));
                mx = fmaxf(mx, __shfl_xor(mx, 8));
                mx2[r] = mx;
            }

            // ---- defer-rescale: only when max grew past THR ---------------
            float growth = -INFINITY;
#pragma unroll
            for (int r = 0; r < 4; ++r) growth = fmaxf(growth, mx2[r] - mrow[r]);
            if (__any(growth > THR)) {
#pragma unroll
                for (int r = 0; r < 4; ++r) {
                    float mnew = fmaxf(mrow[r], mx2[r]);
                    float fac = exp2f(mrow[r] - mnew);   // 0 at t=0
                    mrow[r] = mnew;
                    lrow[r] *= fac;
#pragma unroll
                    for (int ds = 0; ds < 4; ++ds) o[ds][r] *= fac;
                }
            }

            // ---- P = exp2(S - m); lane-local l partials; store kv 0..63 ---
#pragma unroll
            for (int r = 0; r < 4; ++r) {
                float m = mrow[r];
                float rs = 0.f;
#pragma unroll
                for (int ns = 0; ns < 8; ++ns) {
                    float p = exp2f(s[ns][r] - m);
                    s[ns][r] = p;
                    rs += p;
                }
                lrow[r] += rs;
                int prow = g * 4 + r;
#pragma unroll
                for (int ns = 0; ns < 4; ++ns)
                    Ps[w][prow * 72 + ns * 16 + c15] = f2bf_fast(s[ns][r]);
            }

            // ---- mid barrier: Vt/Ps visible; lgkm-only (prefetch flies) ---
            asm volatile("s_waitcnt lgkmcnt(0)" ::: "memory");
            __builtin_amdgcn_s_barrier();
            __builtin_amdgcn_sched_barrier(0);

            // ---- O += P @ V, kv 0..63 -------------------------------------
#pragma unroll
            for (int ks = 0; ks < 2; ++ks) {
                s16x8 pf, vf[4];
                pf = *reinterpret_cast<const s16x8*>(&Ps[w][c15 * 72 + ks * 32 + g * 8]);
#pragma unroll
                for (int ds = 0; ds < 4; ++ds)
                    vf[ds] = *reinterpret_cast<const s16x8*>(&Vt[(ds * 16 + c15) * 136 + ks * 32 + g * 8]);
                __builtin_amdgcn_s_setprio(1);
#pragma unroll
                for (int ds = 0; ds < 4; ++ds)
                    o[ds] = mfma16(pf, vf[ds], o[ds]);
                __builtin_amdgcn_s_setprio(0);
            }
            // ---- store kv 64..127 then second PV pass ---------------------
#pragma unroll
            for (int r = 0; r < 4; ++r) {
                int prow = g * 4 + r;
#pragma unroll
                for (int ns = 0; ns < 4; ++ns)
                    Ps[w][prow * 72 + ns * 16 + c15] = f2bf_fast(s[ns + 4][r]);
            }
#pragma unroll
            for (int ks = 2; ks < 4; ++ks) {
                s16x8 pf, vf[4];
                pf = *reinterpret_cast<const s16x8*>(&Ps[w][c15 * 72 + (ks - 2) * 32 + g * 8]);
#pragma unroll
                for (int ds = 0; ds < 4; ++ds)
                    vf[ds] = *reinterpret_cast<const s16x8*>(&Vt[(ds * 16 + c15) * 136 + ks * 32 + g * 8]);
                __builtin_amdgcn_s_setprio(1);
#pragma unroll
                for (int ds = 0; ds < 4; ++ds)
                    o[ds] = mfma16(pf, vf[ds], o[ds]);
                __builtin_amdgcn_s_setprio(0);
            }

            // ---- end barrier: Vt reuse fence + prefetch drain -------------
            __syncthreads();
            vv0 = nv0;
            vv1 = nv1;
        }

        // ---- epilogue: reduce l partials across the 16-lane row group -----
#pragma unroll
        for (int r = 0; r < 4; ++r) {
            float l = lrow[r];
            l += __shfl_xor(l, 1);
            l += __shfl_xor(l, 2);
            l += __shfl_xor(l, 4);
            l += __shfl_xor(l, 8);
            float inv = 1.0f / l;
            int qrow = qg0 + g * 4 + r;
#pragma unroll
            for (int ds = 0; ds < 4; ++ds)
                outp[(size_t)(b * T + qrow) * 2048 + h * 64 + ds * 16 + c15] =
                    f2bf_fast(o[ds][r] * inv);
        }
    }
#undef KSTAGE
#undef VLOAD
#undef VWRITE
}

// ---------------------------------------------------------------------------
extern "C" void kernel_launch(void* const* d_in, const int* in_sizes, int n_in,
                              void* d_out, int out_size, void* d_ws, size_t ws_size,
                              hipStream_t stream) {
    const float* x  = (const float*)d_in[0];
    const float* wq = (const float*)d_in[1];
    const float* wk = (const float*)d_in[2];
    const float* wv = (const float*)d_in[3];
    const float* wo = (const float*)d_in[4];

    u16* xb   = (u16*)d_ws;            // 8,388,608  : x bf16 [4096][2048]
    u16* wqkv = xb + 8388608;          // 6,291,456  : [3072][2048] (q|k|v rows)
    u16* wob  = wqkv + 6291456;        // 4,194,304  : [2048][2048]
    u16* qkvb = wob + 4194304;         // 12,582,912 : [4096][3072]
    u16* attb = qkvb + 12582912;       // 8,388,608  : [4096][2048]

    cvt_f32_bf16<<<4096, 256, 0, stream>>>(x, xb, 1048576);
    cvt_weights<<<5120, 256, 0, stream>>>(wq, wk, wv, wo, wqkv, wob);

    // Q columns (n0 < 2048) pre-scaled by softmax scale * log2(e)
    gemm_bt<1><<<768, 256, 0, stream>>>(xb, wqkv, qkvb, 4096, 3072, 2048, 24, 2048);
    attn_fwd<<<512, 512, 0, stream>>>(qkvb, attb);
    gemm_bt<0><<<512, 256, 0, stream>>>(attb, wob, d_out, 4096, 2048, 2048, 16, 0);
}